// Round 3
// baseline (217.029 us; speedup 1.0000x reference)
//
#include <hip/hip_runtime.h>
#include <stdint.h>

// B=4, T=1024, DIN=512, DLIN=1024, DK=DV=1024, NH=16, dk=dv=64
// h = data @ W_in[:, :512]^T + W_in[:, 512+t]   (identity concat == column bias)
// q/k/v = h @ W^T ; per-head attention, no max-subtract needed (logits ~ +-0.5).
// Q is pre-scaled by 0.125*log2(e) in the QKV GEMM epilogue so attention's
// softmax is a bare v_exp_f32 (exp2) per element.

typedef __bf16 bf16x8 __attribute__((ext_vector_type(8)));
typedef __bf16 bf16x4v __attribute__((ext_vector_type(4)));
typedef float f32x4 __attribute__((ext_vector_type(4)));
typedef float f32x16 __attribute__((ext_vector_type(16)));
typedef unsigned short u16;
typedef u16 u16x8 __attribute__((ext_vector_type(8)));

#define MFMA16(a, b, c) __builtin_amdgcn_mfma_f32_16x16x32_bf16(a, b, c, 0, 0, 0)
#define MFMA32(a, b, c) __builtin_amdgcn_mfma_f32_32x32x16_bf16(a, b, c, 0, 0, 0)

using gld_src_t = const __attribute__((address_space(1))) unsigned int*;
using gld_dst_t = __attribute__((address_space(3))) unsigned int*;

__device__ __forceinline__ u16 f2bf(float f) {
  uint32_t u = __builtin_bit_cast(uint32_t, f);
  uint32_t r = (u + 0x7fffu + ((u >> 16) & 1u)) >> 16;
  return (u16)r;
}

// ---------------- conversions ----------------

__global__ __launch_bounds__(256) void cvt_all(
    const float* __restrict__ data, const float* __restrict__ wq,
    const float* __restrict__ wk, const float* __restrict__ wv,
    u16* __restrict__ o_data, u16* __restrict__ o_wq,
    u16* __restrict__ o_wk, u16* __restrict__ o_wv) {
  const float* s;
  u16* o;
  int n;
  switch (blockIdx.y) {
    case 0: s = data; o = o_data; n = 4096 * 512; break;
    case 1: s = wq; o = o_wq; n = 1024 * 1024; break;
    case 2: s = wk; o = o_wk; n = 1024 * 1024; break;
    default: s = wv; o = o_wv; n = 1024 * 1024; break;
  }
  int i = (blockIdx.x * 256 + threadIdx.x) * 8;
  if (i >= n) return;
  float4 a = *(const float4*)(s + i);
  float4 b = *(const float4*)(s + i + 4);
  u16x8 v;
  v[0] = f2bf(a.x); v[1] = f2bf(a.y); v[2] = f2bf(a.z); v[3] = f2bf(a.w);
  v[4] = f2bf(b.x); v[5] = f2bf(b.y); v[6] = f2bf(b.z); v[7] = f2bf(b.w);
  *(u16x8*)(o + i) = v;
}

__global__ __launch_bounds__(256) void cvt_win(const float* __restrict__ Win,
                                               u16* __restrict__ wd) {
  int i = (blockIdx.x * 256 + threadIdx.x) * 8;  // over 1024*512
  if (i >= 1024 * 512) return;
  int row = i >> 9, col = i & 511;
  const float* s = Win + (size_t)row * 1536 + col;
  float4 a = *(const float4*)s;
  float4 b = *(const float4*)(s + 4);
  u16x8 v;
  v[0] = f2bf(a.x); v[1] = f2bf(a.y); v[2] = f2bf(a.z); v[3] = f2bf(a.w);
  v[4] = f2bf(b.x); v[5] = f2bf(b.y); v[6] = f2bf(b.z); v[7] = f2bf(b.w);
  *(u16x8*)(wd + i) = v;
}

// ---------------- GEMM: C[4096,1024] = A[4096,K] @ Bw[1024,K]^T ----------------

template <int EPI>
__global__ __launch_bounds__(256) void gemm_bt(
    const u16* __restrict__ A, const u16* __restrict__ B0,
    const u16* __restrict__ B1, const u16* __restrict__ B2,
    const float* __restrict__ Wpos, u16* __restrict__ O0,
    u16* __restrict__ O1, u16* __restrict__ O2, int K) {
  __shared__ u16 Ash[128 * 64];
  __shared__ u16 Bsh[128 * 64];
  const int tid = threadIdx.x;
  const int lane = tid & 63;
  const int w = tid >> 6;
  const int wr = w >> 1, wc = w & 1;
  const int m0 = blockIdx.x * 128, n0 = blockIdx.y * 128;

  const u16* Bw;
  u16* Out;
  if constexpr (EPI == 0) {
    Bw = B0; Out = O0;
  } else {
    int z = blockIdx.z;
    Bw = (z == 0) ? B0 : (z == 1) ? B1 : B2;
    Out = (z == 0) ? O0 : (z == 1) ? O1 : O2;
  }

  f32x4 acc[4][4];
#pragma unroll
  for (int m = 0; m < 4; ++m)
#pragma unroll
    for (int n = 0; n < 4; ++n) acc[m][n] = (f32x4){0.f, 0.f, 0.f, 0.f};

  for (int kt = 0; kt < K; kt += 64) {
    __syncthreads();
#pragma unroll
    for (int i = 0; i < 4; ++i) {
      int c = i * 256 + tid;
      int row = c >> 3;
      int sg = (c & 7) ^ (row & 7);
      const u16* srcA = A + (size_t)(m0 + row) * K + kt + sg * 8;
      __builtin_amdgcn_global_load_lds((gld_src_t)srcA,
                                       (gld_dst_t)&Ash[(i * 256 + w * 64) * 8],
                                       16, 0, 0);
      const u16* srcB = Bw + (size_t)(n0 + row) * K + kt + sg * 8;
      __builtin_amdgcn_global_load_lds((gld_src_t)srcB,
                                       (gld_dst_t)&Bsh[(i * 256 + w * 64) * 8],
                                       16, 0, 0);
    }
    __syncthreads();
#pragma unroll
    for (int kk = 0; kk < 2; ++kk) {
      bf16x8 af[4], bfr[4];
#pragma unroll
      for (int m = 0; m < 4; ++m) {
        int r = wr * 64 + m * 16 + (lane & 15);
        int slot = (kk * 4 + (lane >> 4)) ^ (r & 7);
        af[m] = *(const bf16x8*)((const char*)Ash + r * 128 + slot * 16);
      }
#pragma unroll
      for (int n = 0; n < 4; ++n) {
        int r = wc * 64 + n * 16 + (lane & 15);
        int slot = (kk * 4 + (lane >> 4)) ^ (r & 7);
        bfr[n] = *(const bf16x8*)((const char*)Bsh + r * 128 + slot * 16);
      }
#pragma unroll
      for (int m = 0; m < 4; ++m)
#pragma unroll
        for (int n = 0; n < 4; ++n) acc[m][n] = MFMA16(af[m], bfr[n], acc[m][n]);
    }
  }

  // epilogue; C/D layout: col = lane&15, row = (lane>>4)*4 + reg
#pragma unroll
  for (int m = 0; m < 4; ++m) {
#pragma unroll
    for (int n = 0; n < 4; ++n) {
      int r0 = m0 + wr * 64 + m * 16 + ((lane >> 4) << 2);
      int col = n0 + wc * 64 + n * 16 + (lane & 15);
      if constexpr (EPI == 0) {
        int t0 = r0 & 1023;
        float4 pb = *(const float4*)(Wpos + (size_t)col * 1536 + 512 + t0);
        float pbv[4] = {pb.x, pb.y, pb.z, pb.w};
#pragma unroll
        for (int q = 0; q < 4; ++q)
          Out[(size_t)(r0 + q) * 1024 + col] = f2bf(acc[m][n][q] + pbv[q]);
      } else {
        // z==0 (Q): fold softmax scale * log2(e) so attention exp is bare exp2
        float qsc = (blockIdx.z == 0) ? 0.18033688011112042f : 1.0f;
        int hd = col >> 6, j = col & 63;
        int b = r0 >> 10;
        size_t bh = (size_t)(b * 16 + hd) * 65536;
#pragma unroll
        for (int q = 0; q < 4; ++q) {
          int t = (r0 + q) & 1023;
          size_t idx = (blockIdx.z == 2) ? bh + (size_t)j * 1024 + t
                                         : bh + (size_t)t * 64 + j;
          Out[idx] = f2bf(acc[m][n][q] * qsc);
        }
      }
    }
  }
}

// ---------------- attention (barrier-free, LDS-free main loop) ----------------
// One wave owns 32 q-rows. Swapped QK^T: S^T = mfma(A=K, B=Q) -> lane holds
// S^T[kv][q=lane&31] for 16 kv rows (kv = (r&3)+8*(r>>2)+4*hi). Softmax is
// lane-local plain exp2 (Q pre-scaled). PV uses the k-slot relabeling trick:
// B-frag[s][j] = P[8s+j] directly from the lane's own registers; V A-frag is
// loaded as two 8B chunks matching the same kv permutation. Final O^T -> LDS
// transpose (per-wave buffer, ld=66: 2-way bank alias = free) -> float4 stores.
__global__ __launch_bounds__(256, 2) void attn(const u16* __restrict__ Q,
                                               const u16* __restrict__ K,
                                               const u16* __restrict__ Vt,
                                               float* __restrict__ out) {
  __shared__ float lbuf[4][32 * 66];
  const int tid = threadIdx.x, lane = tid & 63, w = tid >> 6;
  const int q = lane & 31, hi = lane >> 5;
  // XCD swizzle: flat%8 = bh-group so each XCD's L2 holds 8 bh (2MB K+V)
  const int flat = blockIdx.x;
  const int bh = (flat & 7) * 8 + ((flat >> 3) & 7);
  const int q0 = (flat >> 6) * 128 + w * 32;
  const size_t base = (size_t)bh * 65536;

  // Q B-frags: col=q, k = ks*16 + hi*8 + j
  bf16x8 qf[4];
#pragma unroll
  for (int ks = 0; ks < 4; ++ks)
    qf[ks] = *(const bf16x8*)(Q + base + (size_t)(q0 + q) * 64 + ks * 16 + hi * 8);

  f32x16 ot[2];
#pragma unroll
  for (int r = 0; r < 16; ++r) {
    ot[0][r] = 0.f;
    ot[1][r] = 0.f;
  }
  float lsum = 0.f;

  const u16* Kp = K + base + (size_t)q * 64 + hi * 8;
  const u16* Vp = Vt + base + (size_t)q * 1024 + hi * 4;

  for (int kv0 = 0; kv0 < 1024; kv0 += 32) {
    f32x16 st;
#pragma unroll
    for (int r = 0; r < 16; ++r) st[r] = 0.f;
#pragma unroll
    for (int ks = 0; ks < 4; ++ks) {
      bf16x8 kf = *(const bf16x8*)(Kp + (size_t)kv0 * 64 + ks * 16);
      st = MFMA32(kf, qf[ks], st);
    }
    float pe[16];
#pragma unroll
    for (int r = 0; r < 16; ++r) pe[r] = __builtin_exp2f(st[r]);
    {  // pairwise tree to shorten the dep chain
      float t0 = (pe[0] + pe[1]) + (pe[2] + pe[3]);
      float t1 = (pe[4] + pe[5]) + (pe[6] + pe[7]);
      float t2 = (pe[8] + pe[9]) + (pe[10] + pe[11]);
      float t3 = (pe[12] + pe[13]) + (pe[14] + pe[15]);
      lsum += (t0 + t1) + (t2 + t3);
    }
#pragma unroll
    for (int s = 0; s < 2; ++s) {
      bf16x8 pf;
#pragma unroll
      for (int j = 0; j < 8; ++j) pf[j] = (__bf16)pe[8 * s + j];
#pragma unroll
      for (int d = 0; d < 2; ++d) {
        const u16* vr = Vp + (size_t)(32 * d) * 1024 + kv0 + 16 * s;
        bf16x4v v0 = *(const bf16x4v*)vr;
        bf16x4v v1 = *(const bf16x4v*)(vr + 8);
        bf16x8 vf;
#pragma unroll
        for (int j = 0; j < 4; ++j) {
          vf[j] = v0[j];
          vf[4 + j] = v1[j];
        }
        ot[d] = MFMA32(vf, pf, ot[d]);
      }
    }
  }

  // combine the two kv-halves held by lane pair (l, l+32); both have same q
  lsum += __shfl_xor(lsum, 32, 64);
  float ri = 1.0f / lsum;

  float* lb = &lbuf[w][0];
#pragma unroll
  for (int d = 0; d < 2; ++d)
#pragma unroll
    for (int rr = 0; rr < 16; rr += 2) {
      int dv = 32 * d + (rr & 3) + 8 * (rr >> 2) + 4 * hi;
      *(float2*)(lb + q * 66 + dv) =
          make_float2(ot[d][rr] * ri, ot[d][rr + 1] * ri);
    }
  __syncthreads();
  const int b = bh >> 4, hd = bh & 15;
#pragma unroll
  for (int i = 0; i < 8; ++i) {
    int row = i * 4 + (lane >> 4);
    const float* lr = lb + row * 66 + (lane & 15) * 4;
    float2 x0 = *(const float2*)lr;
    float2 x1 = *(const float2*)(lr + 2);
    float4 v = make_float4(x0.x, x0.y, x1.x, x1.y);
    *(float4*)(out + ((size_t)(b * 1024 + q0 + row)) * 1024 + hd * 64 +
               (lane & 15) * 4) = v;
  }
}

// ---------------- launch ----------------

extern "C" void kernel_launch(void* const* d_in, const int* in_sizes, int n_in,
                              void* d_out, int out_size, void* d_ws,
                              size_t ws_size, hipStream_t stream) {
  const float* data = (const float*)d_in[0];
  const float* Win = (const float*)d_in[1];
  const float* Wq = (const float*)d_in[2];
  const float* Wk = (const float*)d_in[3];
  const float* Wv = (const float*)d_in[4];
  float* out = (float*)d_out;

  char* ws = (char*)d_ws;
  u16* data_b = (u16*)ws; ws += (size_t)4096 * 512 * 2;
  u16* wd_b = (u16*)ws;   ws += (size_t)1024 * 512 * 2;
  u16* wq_b = (u16*)ws;   ws += (size_t)1024 * 1024 * 2;
  u16* wk_b = (u16*)ws;   ws += (size_t)1024 * 1024 * 2;
  u16* wv_b = (u16*)ws;   ws += (size_t)1024 * 1024 * 2;
  u16* h_b = (u16*)ws;    ws += (size_t)4096 * 1024 * 2;
  u16* q_b = (u16*)ws;    ws += (size_t)4194304 * 2;  // [bh][t][64], pre-scaled
  u16* k_b = (u16*)ws;    ws += (size_t)4194304 * 2;  // [bh][t][64]
  u16* vt_b = (u16*)ws;   ws += (size_t)4194304 * 2;  // [bh][64][t]

  cvt_all<<<dim3(1024, 4), 256, 0, stream>>>(data, Wq, Wk, Wv, data_b, wq_b,
                                             wk_b, wv_b);
  cvt_win<<<dim3(256), 256, 0, stream>>>(Win, wd_b);
  gemm_bt<0><<<dim3(32, 8, 1), 256, 0, stream>>>(data_b, wd_b, wd_b, wd_b, Win,
                                                 h_b, h_b, h_b, 512);
  gemm_bt<1><<<dim3(32, 8, 3), 256, 0, stream>>>(h_b, wq_b, wk_b, wv_b, nullptr,
                                                 q_b, k_b, vt_b, 1024);
  attn<<<dim3(512), 256, 0, stream>>>(q_b, k_b, vt_b, out);
}

// Round 6
// 193.598 us; speedup vs baseline: 1.1210x; 1.1210x over previous
//
#include <hip/hip_runtime.h>
#include <stdint.h>

// B=4, T=1024, DIN=512, DLIN=1024, DK=DV=1024, NH=16, dk=dv=64
// h = data @ W_in[:, :512]^T + W_in[:, 512+t]   (identity concat == column bias)
// q/k/v = h @ W^T ; per-head attention, no max-subtract needed (logits ~ +-0.5).
// Q pre-scaled by 0.125*log2(e) in the QKV GEMM epilogue -> softmax is bare exp2.
// V^T stored with kv bits 2<->3 swapped (phi involution) so the PV A-fragment
// is a single 16B load per lane matching P's k-slot relabeling.

typedef __bf16 bf16x8 __attribute__((ext_vector_type(8)));
typedef float f32x4 __attribute__((ext_vector_type(4)));
typedef float f32x16 __attribute__((ext_vector_type(16)));
typedef unsigned short u16;
typedef u16 u16x8 __attribute__((ext_vector_type(8)));

#define MFMA16(a, b, c) __builtin_amdgcn_mfma_f32_16x16x32_bf16(a, b, c, 0, 0, 0)
#define MFMA32(a, b, c) __builtin_amdgcn_mfma_f32_32x32x16_bf16(a, b, c, 0, 0, 0)

using gld_src_t = const __attribute__((address_space(1))) unsigned int*;
using gld_dst_t = __attribute__((address_space(3))) unsigned int*;

__device__ __forceinline__ u16 f2bf(float f) {
  uint32_t u = __builtin_bit_cast(uint32_t, f);
  uint32_t r = (u + 0x7fffu + ((u >> 16) & 1u)) >> 16;
  return (u16)r;
}

// ---------------- conversions ----------------

__global__ __launch_bounds__(256) void cvt_all(
    const float* __restrict__ data, const float* __restrict__ wq,
    const float* __restrict__ wk, const float* __restrict__ wv,
    u16* __restrict__ o_data, u16* __restrict__ o_wq,
    u16* __restrict__ o_wk, u16* __restrict__ o_wv) {
  const float* s;
  u16* o;
  int n;
  switch (blockIdx.y) {
    case 0: s = data; o = o_data; n = 4096 * 512; break;
    case 1: s = wq; o = o_wq; n = 1024 * 1024; break;
    case 2: s = wk; o = o_wk; n = 1024 * 1024; break;
    default: s = wv; o = o_wv; n = 1024 * 1024; break;
  }
  int i = (blockIdx.x * 256 + threadIdx.x) * 8;
  if (i >= n) return;
  float4 a = *(const float4*)(s + i);
  float4 b = *(const float4*)(s + i + 4);
  u16x8 v;
  v[0] = f2bf(a.x); v[1] = f2bf(a.y); v[2] = f2bf(a.z); v[3] = f2bf(a.w);
  v[4] = f2bf(b.x); v[5] = f2bf(b.y); v[6] = f2bf(b.z); v[7] = f2bf(b.w);
  *(u16x8*)(o + i) = v;
}

__global__ __launch_bounds__(256) void cvt_win(const float* __restrict__ Win,
                                               u16* __restrict__ wd) {
  int i = (blockIdx.x * 256 + threadIdx.x) * 8;  // over 1024*512
  if (i >= 1024 * 512) return;
  int row = i >> 9, col = i & 511;
  const float* s = Win + (size_t)row * 1536 + col;
  float4 a = *(const float4*)s;
  float4 b = *(const float4*)(s + 4);
  u16x8 v;
  v[0] = f2bf(a.x); v[1] = f2bf(a.y); v[2] = f2bf(a.z); v[3] = f2bf(a.w);
  v[4] = f2bf(b.x); v[5] = f2bf(b.y); v[6] = f2bf(b.z); v[7] = f2bf(b.w);
  *(u16x8*)(wd + i) = v;
}

// ---------------- GEMM: C[4096,1024] = A[4096,K] @ Bw[1024,K]^T ----------------

template <int EPI>
__global__ __launch_bounds__(256) void gemm_bt(
    const u16* __restrict__ A, const u16* __restrict__ B0,
    const u16* __restrict__ B1, const u16* __restrict__ B2,
    const float* __restrict__ Wpos, u16* __restrict__ O0,
    u16* __restrict__ O1, u16* __restrict__ O2, int K) {
  __shared__ u16 Ash[128 * 64];
  __shared__ u16 Bsh[128 * 64];
  const int tid = threadIdx.x;
  const int lane = tid & 63;
  const int w = tid >> 6;
  const int wr = w >> 1, wc = w & 1;
  const int m0 = blockIdx.x * 128, n0 = blockIdx.y * 128;

  const u16* Bw;
  u16* Out;
  if constexpr (EPI == 0) {
    Bw = B0; Out = O0;
  } else {
    int z = blockIdx.z;
    Bw = (z == 0) ? B0 : (z == 1) ? B1 : B2;
    Out = (z == 0) ? O0 : (z == 1) ? O1 : O2;
  }

  f32x4 acc[4][4];
#pragma unroll
  for (int m = 0; m < 4; ++m)
#pragma unroll
    for (int n = 0; n < 4; ++n) acc[m][n] = (f32x4){0.f, 0.f, 0.f, 0.f};

  for (int kt = 0; kt < K; kt += 64) {
    __syncthreads();
#pragma unroll
    for (int i = 0; i < 4; ++i) {
      int c = i * 256 + tid;
      int row = c >> 3;
      int sg = (c & 7) ^ (row & 7);
      const u16* srcA = A + (size_t)(m0 + row) * K + kt + sg * 8;
      __builtin_amdgcn_global_load_lds((gld_src_t)srcA,
                                       (gld_dst_t)&Ash[(i * 256 + w * 64) * 8],
                                       16, 0, 0);
      const u16* srcB = Bw + (size_t)(n0 + row) * K + kt + sg * 8;
      __builtin_amdgcn_global_load_lds((gld_src_t)srcB,
                                       (gld_dst_t)&Bsh[(i * 256 + w * 64) * 8],
                                       16, 0, 0);
    }
    __syncthreads();
#pragma unroll
    for (int kk = 0; kk < 2; ++kk) {
      bf16x8 af[4], bfr[4];
#pragma unroll
      for (int m = 0; m < 4; ++m) {
        int r = wr * 64 + m * 16 + (lane & 15);
        int slot = (kk * 4 + (lane >> 4)) ^ (r & 7);
        af[m] = *(const bf16x8*)((const char*)Ash + r * 128 + slot * 16);
      }
#pragma unroll
      for (int n = 0; n < 4; ++n) {
        int r = wc * 64 + n * 16 + (lane & 15);
        int slot = (kk * 4 + (lane >> 4)) ^ (r & 7);
        bfr[n] = *(const bf16x8*)((const char*)Bsh + r * 128 + slot * 16);
      }
#pragma unroll
      for (int m = 0; m < 4; ++m)
#pragma unroll
        for (int n = 0; n < 4; ++n) acc[m][n] = MFMA16(af[m], bfr[n], acc[m][n]);
    }
  }

  // epilogue; C/D layout: col = lane&15, row = (lane>>4)*4 + reg
#pragma unroll
  for (int m = 0; m < 4; ++m) {
#pragma unroll
    for (int n = 0; n < 4; ++n) {
      int r0 = m0 + wr * 64 + m * 16 + ((lane >> 4) << 2);
      int col = n0 + wc * 64 + n * 16 + (lane & 15);
      if constexpr (EPI == 0) {
        int t0 = r0 & 1023;
        float4 pb = *(const float4*)(Wpos + (size_t)col * 1536 + 512 + t0);
        float pbv[4] = {pb.x, pb.y, pb.z, pb.w};
#pragma unroll
        for (int q = 0; q < 4; ++q)
          Out[(size_t)(r0 + q) * 1024 + col] = f2bf(acc[m][n][q] + pbv[q]);
      } else {
        // z==0 (Q): fold softmax scale * log2(e) so attention exp is bare exp2
        float qsc = (blockIdx.z == 0) ? 0.18033688011112042f : 1.0f;
        int hd = col >> 6, j = col & 63;
        int b = r0 >> 10;
        size_t bh = (size_t)(b * 16 + hd) * 65536;
#pragma unroll
        for (int q = 0; q < 4; ++q) {
          int t = (r0 + q) & 1023;
          // V^T (z==2): swap kv bits 2<->3 (phi involution) for 16B PV loads
          int tp = (t & ~12) | ((t & 4) << 1) | ((t & 8) >> 1);
          size_t idx = (blockIdx.z == 2) ? bh + (size_t)j * 1024 + tp
                                         : bh + (size_t)t * 64 + j;
          Out[idx] = f2bf(acc[m][n][q] * qsc);
        }
      }
    }
  }
}

// ---------------- attention ----------------
// One wave owns 32 q-rows. Swapped QK^T: S^T = mfma(A=K, B=Q) -> lane holds
// S^T[kv][q=lane&31] for 16 kv rows. Softmax lane-local (bare exp2, Q
// pre-scaled). PV feeds P straight from registers as the B operand; V A-frag
// is ONE 16B load thanks to the phi bit-swapped V^T layout. Register
// double-buffer (named A/B tiles, static indexing) hides the L2 latency of
// the 8x16B loads per tile under the previous tile's compute (T14).
__global__ __launch_bounds__(256, 2) void attn(const u16* __restrict__ Q,
                                               const u16* __restrict__ K,
                                               const u16* __restrict__ Vt,
                                               float* __restrict__ out) {
  __shared__ float lbuf[4][32 * 66];
  const int tid = threadIdx.x, lane = tid & 63, w = tid >> 6;
  const int q = lane & 31, hi = lane >> 5;
  // XCD swizzle: flat%8 = bh-group so each XCD's L2 holds 8 bh (2MB K+V)
  const int flat = blockIdx.x;
  const int bh = (flat & 7) * 8 + ((flat >> 3) & 7);
  const int q0 = (flat >> 6) * 128 + w * 32;
  const size_t base = (size_t)bh * 65536;

  // Q B-frags: col=q, k = ks*16 + hi*8 + j
  bf16x8 qf[4];
#pragma unroll
  for (int ks = 0; ks < 4; ++ks)
    qf[ks] = *(const bf16x8*)(Q + base + (size_t)(q0 + q) * 64 + ks * 16 + hi * 8);

  f32x16 ot[2];
#pragma unroll
  for (int r = 0; r < 16; ++r) {
    ot[0][r] = 0.f;
    ot[1][r] = 0.f;
  }
  float lsum = 0.f;

  const u16* Kp = K + base + (size_t)q * 64 + hi * 8;
  const u16* Vp = Vt + base + (size_t)q * 1024 + hi * 8;

  auto loadK = [&](int kv0, bf16x8 (&kb)[4]) {
#pragma unroll
    for (int ks = 0; ks < 4; ++ks)
      kb[ks] = *(const bf16x8*)(Kp + (size_t)kv0 * 64 + ks * 16);
  };
  auto loadV = [&](int kv0, bf16x8 (&vb)[4]) {
#pragma unroll
    for (int s = 0; s < 2; ++s)
#pragma unroll
      for (int d = 0; d < 2; ++d)
        vb[2 * s + d] =
            *(const bf16x8*)(Vp + (size_t)(32 * d) * 1024 + kv0 + 16 * s);
  };
  auto compute = [&](const bf16x8 (&kb)[4], const bf16x8 (&vb)[4]) {
    f32x16 st;
#pragma unroll
    for (int r = 0; r < 16; ++r) st[r] = 0.f;
#pragma unroll
    for (int ks = 0; ks < 4; ++ks) st = MFMA32(kb[ks], qf[ks], st);
    float pe[16];
#pragma unroll
    for (int r = 0; r < 16; ++r) pe[r] = __builtin_exp2f(st[r]);
    {  // pairwise tree to shorten the dep chain
      float t0 = (pe[0] + pe[1]) + (pe[2] + pe[3]);
      float t1 = (pe[4] + pe[5]) + (pe[6] + pe[7]);
      float t2 = (pe[8] + pe[9]) + (pe[10] + pe[11]);
      float t3 = (pe[12] + pe[13]) + (pe[14] + pe[15]);
      lsum += (t0 + t1) + (t2 + t3);
    }
#pragma unroll
    for (int s = 0; s < 2; ++s) {
      bf16x8 pf;
#pragma unroll
      for (int j = 0; j < 8; ++j) pf[j] = (__bf16)pe[8 * s + j];
#pragma unroll
      for (int d = 0; d < 2; ++d) ot[d] = MFMA32(vb[2 * s + d], pf, ot[d]);
    }
  };

  bf16x8 kA[4], vA[4], kB[4], vB[4];
  loadK(0, kA);
  loadV(0, vA);
  for (int kv0 = 0; kv0 < 1024; kv0 += 64) {
    loadK(kv0 + 32, kB);
    loadV(kv0 + 32, vB);
    compute(kA, vA);
    if (kv0 + 64 < 1024) {
      loadK(kv0 + 64, kA);
      loadV(kv0 + 64, vA);
    }
    compute(kB, vB);
  }

  // combine the two kv-halves held by lane pair (l, l+32); both have same q
  lsum += __shfl_xor(lsum, 32, 64);
  float ri = 1.0f / lsum;

  float* lb = &lbuf[w][0];
#pragma unroll
  for (int d = 0; d < 2; ++d)
#pragma unroll
    for (int rr = 0; rr < 16; rr += 2) {
      int dv = 32 * d + (rr & 3) + 8 * (rr >> 2) + 4 * hi;
      *(float2*)(lb + q * 66 + dv) =
          make_float2(ot[d][rr] * ri, ot[d][rr + 1] * ri);
    }
  __syncthreads();
  const int b = bh >> 4, hd = bh & 15;
#pragma unroll
  for (int i = 0; i < 8; ++i) {
    int row = i * 4 + (lane >> 4);
    const float* lr = lb + row * 66 + (lane & 15) * 4;
    float2 x0 = *(const float2*)lr;
    float2 x1 = *(const float2*)(lr + 2);
    float4 v = make_float4(x0.x, x0.y, x1.x, x1.y);
    *(float4*)(out + ((size_t)(b * 1024 + q0 + row)) * 1024 + hd * 64 +
               (lane & 15) * 4) = v;
  }
}

// ---------------- launch ----------------

extern "C" void kernel_launch(void* const* d_in, const int* in_sizes, int n_in,
                              void* d_out, int out_size, void* d_ws,
                              size_t ws_size, hipStream_t stream) {
  const float* data = (const float*)d_in[0];
  const float* Win = (const float*)d_in[1];
  const float* Wq = (const float*)d_in[2];
  const float* Wk = (const float*)d_in[3];
  const float* Wv = (const float*)d_in[4];
  float* out = (float*)d_out;

  char* ws = (char*)d_ws;
  u16* data_b = (u16*)ws; ws += (size_t)4096 * 512 * 2;
  u16* wd_b = (u16*)ws;   ws += (size_t)1024 * 512 * 2;
  u16* wq_b = (u16*)ws;   ws += (size_t)1024 * 1024 * 2;
  u16* wk_b = (u16*)ws;   ws += (size_t)1024 * 1024 * 2;
  u16* wv_b = (u16*)ws;   ws += (size_t)1024 * 1024 * 2;
  u16* h_b = (u16*)ws;    ws += (size_t)4096 * 1024 * 2;
  u16* q_b = (u16*)ws;    ws += (size_t)4194304 * 2;  // [bh][t][64], pre-scaled
  u16* k_b = (u16*)ws;    ws += (size_t)4194304 * 2;  // [bh][t][64]
  u16* vt_b = (u16*)ws;   ws += (size_t)4194304 * 2;  // [bh][64][t] phi-swizzled

  cvt_all<<<dim3(1024, 4), 256, 0, stream>>>(data, Wq, Wk, Wv, data_b, wq_b,
                                             wk_b, wv_b);
  cvt_win<<<dim3(256), 256, 0, stream>>>(Win, wd_b);
  gemm_bt<0><<<dim3(32, 8, 1), 256, 0, stream>>>(data_b, wd_b, wd_b, wd_b, Win,
                                                 h_b, h_b, h_b, 512);
  gemm_bt<1><<<dim3(32, 8, 3), 256, 0, stream>>>(h_b, wq_b, wk_b, wv_b, nullptr,
                                                 q_b, k_b, vt_b, 1024);
  attn<<<dim3(512), 256, 0, stream>>>(q_b, k_b, vt_b, out);
}